// Round 10
// baseline (897.046 us; speedup 1.0000x reference)
//
#include <hip/hip_runtime.h>
#include <math.h>
#include <stdint.h>

#define N_TOK 4096
#define DIM   1024
#define HID   2048
#define NE    8
#define NROWS (N_TOK * 2)   // 8192 (token, k) assignments
#define LDST  72            // LDS tile stride in shorts (36 dwords; balanced banks, 16B-aligned)

typedef __attribute__((ext_vector_type(8))) short bf16x8;
typedef __attribute__((ext_vector_type(4))) float f32x4;

__device__ __forceinline__ unsigned short f2bf(float f) {
    union { unsigned int i; float f; } v; v.f = f;
    unsigned int u = v.i;
    return (unsigned short)((u + 0x7FFFu + ((u >> 16) & 1u)) >> 16);
}
__device__ __forceinline__ int clampi(int v, int lo, int hi) {
    return v < lo ? lo : (v > hi ? hi : v);
}
__device__ __forceinline__ void cvt8(const float* p, unsigned short* o) {
    float4 a = *(const float4*)p;
    float4 b = *(const float4*)(p + 4);
    o[0] = f2bf(a.x); o[1] = f2bf(a.y); o[2] = f2bf(a.z); o[3] = f2bf(a.w);
    o[4] = f2bf(b.x); o[5] = f2bf(b.y); o[6] = f2bf(b.z); o[7] = f2bf(b.w);
}
__device__ __forceinline__ float fast_gelu(float v) {
    float c = 0.7978845608028654f * (v + 0.044715f * v * v * v);
    float t = 1.f - 2.f / (1.f + __expf(2.f * c));   // tanh(c)
    return 0.5f * v * (1.f + t);
}

// ---------------- init: zero header + d_out ----------------
__global__ __launch_bounds__(256) void init_out_kernel(int* __restrict__ hdr, float4* __restrict__ out4) {
    int i = blockIdx.x * 256 + threadIdx.x;     // 4096 blocks -> 1M float4
    out4[i] = make_float4(0.f, 0.f, 0.f, 0.f);
    if (i < 32) hdr[i] = 0;
}

// ---------------- gating: one wave per token, pure fp32 ----------------
__global__ __launch_bounds__(256) void gate_kernel(
    const float* __restrict__ x, const float* __restrict__ wg,
    int* __restrict__ counts, int* __restrict__ top_e, float* __restrict__ top_g)
{
    int wave = threadIdx.x >> 6;
    int lane = threadIdx.x & 63;
    int n = blockIdx.x * 4 + wave;
    if (n >= N_TOK) return;
    float acc[NE];
#pragma unroll
    for (int e = 0; e < NE; e++) acc[e] = 0.f;
    const float* xrow = x + (size_t)n * DIM;
    for (int d = lane; d < DIM; d += 64) {
        float xv = xrow[d];
        float4 wa = *(const float4*)(wg + (size_t)d * NE);
        float4 wb = *(const float4*)(wg + (size_t)d * NE + 4);
        acc[0] += xv * wa.x; acc[1] += xv * wa.y;
        acc[2] += xv * wa.z; acc[3] += xv * wa.w;
        acc[4] += xv * wb.x; acc[5] += xv * wb.y;
        acc[6] += xv * wb.z; acc[7] += xv * wb.w;
    }
#pragma unroll
    for (int e = 0; e < NE; e++) {
        float v = acc[e];
#pragma unroll
        for (int off = 32; off > 0; off >>= 1) v += __shfl_xor(v, off, 64);
        acc[e] = v;
    }
    if (lane == 0) {
        int e0 = 0; float v0 = acc[0];
#pragma unroll
        for (int e = 1; e < NE; e++) if (acc[e] > v0) { v0 = acc[e]; e0 = e; }
        int e1 = (e0 == 0) ? 1 : 0; float v1 = acc[e1];
#pragma unroll
        for (int e = 0; e < NE; e++) if (e != e0 && acc[e] > v1) { v1 = acc[e]; e1 = e; }
        float s = expf(v1 - v0);
        float g0 = 1.f / (1.f + s);
        float g1 = s / (1.f + s);
        atomicAdd(&counts[e0], 1);
        atomicAdd(&counts[e1], 1);
        top_e[n] = e0 | (e1 << 8);
        top_g[2 * n + 0] = g0;
        top_g[2 * n + 1] = g1;
    }
}

// ---------------- scatter: build per-expert row lists ----------------
__global__ __launch_bounds__(256) void scatter_kernel(
    const int* __restrict__ counts, int* __restrict__ cursors,
    const int* __restrict__ top_e, const float* __restrict__ top_g,
    int* __restrict__ row_tok, float* __restrict__ row_gate)
{
    int n = blockIdx.x * 256 + threadIdx.x;
    if (n >= N_TOK) return;
    int off[NE]; int a = 0;
#pragma unroll
    for (int e = 0; e < NE; e++) { off[e] = a; a += clampi(counts[e], 0, NROWS); }
    int te = top_e[n];
#pragma unroll
    for (int k = 0; k < 2; k++) {
        int e = clampi((k == 0) ? (te & 0xFF) : ((te >> 8) & 0xFF), 0, NE - 1);
        int pos = atomicAdd(&cursors[e], 1);
        int r = clampi(off[e] + pos, 0, NROWS - 1);
        row_tok[r]  = n;
        row_gate[r] = top_g[2 * n + k];
    }
}

// ---------------- xgather: xg[gr][:] = bf16(x[row_tok[gr]][:]) ----------------
__global__ __launch_bounds__(256) void xgather_kernel(
    const float* __restrict__ x, const int* __restrict__ row_tok,
    unsigned short* __restrict__ xg)
{
    int id = blockIdx.x * 256 + threadIdx.x;   // NROWS * DIM/8 = 1,048,576
    int row = id >> 7;
    int kc  = (id & 127) * 8;
    int tok = clampi(row_tok[row], 0, N_TOK - 1);
    unsigned short v[8];
    cvt8(x + (size_t)tok * DIM + kc, v);
    *(uint4*)(xg + (size_t)row * DIM + kc) = *(uint4*)v;
}

// ---------------- transpose+cast: in[e][K][N] fp32 -> out[e][N][K] bf16 ----------------
__global__ __launch_bounds__(256) void transpose_kernel(
    const float* __restrict__ in, unsigned short* __restrict__ outp, int K, int N)
{
    int e  = blockIdx.z;
    int kb = blockIdx.x;
    int nb = blockIdx.y;
    __shared__ __align__(16) unsigned short tile[64 * LDST];
    int t = threadIdx.x;

    int r = t >> 2, cq = t & 3;
    const float* sp = in + ((size_t)e * K + kb * 64 + r) * N + nb * 64 + cq * 16;
    unsigned short v[16];
    cvt8(sp, v);
    cvt8(sp + 8, v + 8);
    *(uint4*)(&tile[r * LDST + cq * 16 + 0]) = *(uint4*)(v + 0);
    *(uint4*)(&tile[r * LDST + cq * 16 + 8]) = *(uint4*)(v + 8);
    __syncthreads();

    int c = t >> 2, kq = t & 3;
    unsigned short o[16];
#pragma unroll
    for (int i = 0; i < 16; i++) o[i] = tile[(kq * 16 + i) * LDST + c];
    unsigned short* dp = outp + ((size_t)e * N + nb * 64 + c) * K + kb * 64 + kq * 16;
    *(uint4*)(dp + 0) = *(uint4*)(o + 0);
    *(uint4*)(dp + 8) = *(uint4*)(o + 8);
}

// ---------------- FFN1 v2: 128x128, BK=64, prefetch dbuf, xg/w1t bf16 ----------------
__global__ __launch_bounds__(256) void ffn1_fast2(
    const unsigned short* __restrict__ xg,    // [NROWS][DIM] grouped bf16
    const unsigned short* __restrict__ w1t,   // [e][H][D] bf16
    const float* __restrict__ b1,
    const int* __restrict__ counts,
    unsigned short* __restrict__ h)
{
    int id = blockIdx.x;
    int nb = id % (HID / 128);
    int rest = id / (HID / 128);
    int e  = rest % NE;
    int mb = rest / NE;

    int off = 0;
#pragma unroll
    for (int i = 0; i < NE; i++) { int c = clampi(counts[i], 0, NROWS); if (i < e) off += c; }
    int cnt  = clampi(counts[e], 0, NROWS);
    int row0 = mb * 128;
    if (row0 >= cnt) return;
    int nvalid = clampi(cnt - row0, 1, 128);
    int gr0 = off + row0;

    __shared__ __align__(16) unsigned short lA[128 * LDST];
    __shared__ __align__(16) unsigned short lB[128 * LDST];

    int t = threadIdx.x;
    const int n0 = nb * 128;
    const unsigned short* aptr[4];
    const unsigned short* bptr[4];
    int lofs[4];
#pragma unroll
    for (int i = 0; i < 4; i++) {
        int id2 = i * 256 + t;
        int row = id2 >> 3, kc = id2 & 7;
        int arow = clampi(gr0 + row, 0, NROWS - 1);   // tail rows may spill past 8192
        aptr[i] = xg + (size_t)arow * DIM + kc * 8;
        bptr[i] = w1t + ((size_t)e * HID + n0 + row) * DIM + kc * 8;
        lofs[i] = row * LDST + kc * 8;
    }

    int wv = t >> 6, lane = t & 63, quad = lane >> 4, ln = lane & 15;
    int wr = wv >> 1, wc = wv & 1;
    f32x4 acc[4][4];
#pragma unroll
    for (int i = 0; i < 4; i++)
#pragma unroll
        for (int j = 0; j < 4; j++) acc[i][j] = (f32x4){0.f, 0.f, 0.f, 0.f};

    uint4 ra[4], rb[4];
#pragma unroll
    for (int i = 0; i < 4; i++) { ra[i] = *(const uint4*)(aptr[i]); rb[i] = *(const uint4*)(bptr[i]); }

    for (int kt = 0; kt < DIM / 64; kt++) {
        __syncthreads();                       // readers of previous tile done
#pragma unroll
        for (int i = 0; i < 4; i++) {
            *(uint4*)(&lA[lofs[i]]) = ra[i];
            *(uint4*)(&lB[lofs[i]]) = rb[i];
        }
        __syncthreads();
        if (kt + 1 < DIM / 64) {               // prefetch next tile during MFMA phase
            int k0 = (kt + 1) * 64;
#pragma unroll
            for (int i = 0; i < 4; i++) {
                ra[i] = *(const uint4*)(aptr[i] + k0);
                rb[i] = *(const uint4*)(bptr[i] + k0);
            }
        }
#pragma unroll
        for (int kk = 0; kk < 2; kk++) {
            bf16x8 af[4], bf[4];
#pragma unroll
            for (int s = 0; s < 4; s++)
                af[s] = *(const bf16x8*)(&lA[(wr * 64 + s * 16 + ln) * LDST + kk * 32 + quad * 8]);
#pragma unroll
            for (int s = 0; s < 4; s++)
                bf[s] = *(const bf16x8*)(&lB[(wc * 64 + s * 16 + ln) * LDST + kk * 32 + quad * 8]);
#pragma unroll
            for (int i = 0; i < 4; i++)
#pragma unroll
                for (int j = 0; j < 4; j++)
                    acc[i][j] = __builtin_amdgcn_mfma_f32_16x16x32_bf16(af[i], bf[j], acc[i][j], 0, 0, 0);
        }
    }

#pragma unroll
    for (int j = 0; j < 4; j++) {
        int col = n0 + wc * 64 + j * 16 + ln;
        float bias = b1[e * HID + col];
#pragma unroll
        for (int i = 0; i < 4; i++) {
#pragma unroll
            for (int r = 0; r < 4; r++) {
                int m = wr * 64 + i * 16 + quad * 4 + r;
                if (m < nvalid)
                    h[(size_t)(gr0 + m) * HID + col] = f2bf(fast_gelu(acc[i][j][r] + bias));
            }
        }
    }
}

// ---------------- FFN2 v2: 128x64, BK=64, prefetch dbuf, atomic into out ----------------
__global__ __launch_bounds__(256) void ffn2_fast2(
    const unsigned short* __restrict__ hb,    // [NROWS][HID] bf16
    const unsigned short* __restrict__ w2t,   // [e][D][H] bf16
    const float* __restrict__ b2,
    const int* __restrict__ counts,
    const int* __restrict__ row_tok,
    const float* __restrict__ row_gate,
    float* __restrict__ out)
{
    int id = blockIdx.x;
    int nb = id % (DIM / 64);
    int rest = id / (DIM / 64);
    int e  = rest % NE;
    int mb = rest / NE;

    int off = 0;
#pragma unroll
    for (int i = 0; i < NE; i++) { int c = clampi(counts[i], 0, NROWS); if (i < e) off += c; }
    int cnt  = clampi(counts[e], 0, NROWS);
    int row0 = mb * 128;
    if (row0 >= cnt) return;
    int nvalid = clampi(cnt - row0, 1, 128);
    int gr0 = off + row0;

    __shared__ __align__(16) unsigned short lA[128 * LDST];
    __shared__ __align__(16) unsigned short lB[64 * LDST];
    __shared__ int   ltok2[128];
    __shared__ float lgate[128];

    int t = threadIdx.x;
    if (t < 128) {
        int rl = clampi(t, 0, nvalid - 1);
        int idx = clampi(gr0 + rl, 0, NROWS - 1);
        ltok2[t] = clampi(row_tok[idx], 0, N_TOK - 1);
        lgate[t] = row_gate[idx];
    }

    const int n0 = nb * 64;
    const unsigned short* aptr[4];
    int laofs[4];
#pragma unroll
    for (int i = 0; i < 4; i++) {
        int id2 = i * 256 + t;
        int row = id2 >> 3, kc = id2 & 7;
        int arow = clampi(gr0 + row, 0, NROWS - 1);
        aptr[i] = hb + (size_t)arow * HID + kc * 8;
        laofs[i] = row * LDST + kc * 8;
    }
    const unsigned short* bptr[2];
    int lbofs[2];
#pragma unroll
    for (int i = 0; i < 2; i++) {
        int id2 = i * 256 + t;
        int row = id2 >> 3, kc = id2 & 7;
        bptr[i] = w2t + ((size_t)e * DIM + n0 + row) * HID + kc * 8;
        lbofs[i] = row * LDST + kc * 8;
    }

    int wv = t >> 6, lane = t & 63, quad = lane >> 4, ln = lane & 15;
    int wr = wv >> 1, wc = wv & 1;        // 2x2 wave grid: 64 rows x 32 cols each
    f32x4 acc[4][2];
#pragma unroll
    for (int i = 0; i < 4; i++)
#pragma unroll
        for (int j = 0; j < 2; j++) acc[i][j] = (f32x4){0.f, 0.f, 0.f, 0.f};

    uint4 ra[4], rb[2];
#pragma unroll
    for (int i = 0; i < 4; i++) ra[i] = *(const uint4*)(aptr[i]);
#pragma unroll
    for (int i = 0; i < 2; i++) rb[i] = *(const uint4*)(bptr[i]);

    for (int kt = 0; kt < HID / 64; kt++) {
        __syncthreads();
#pragma unroll
        for (int i = 0; i < 4; i++) *(uint4*)(&lA[laofs[i]]) = ra[i];
#pragma unroll
        for (int i = 0; i < 2; i++) *(uint4*)(&lB[lbofs[i]]) = rb[i];
        __syncthreads();
        if (kt + 1 < HID / 64) {
            int k0 = (kt + 1) * 64;
#pragma unroll
            for (int i = 0; i < 4; i++) ra[i] = *(const uint4*)(aptr[i] + k0);
#pragma unroll
            for (int i = 0; i < 2; i++) rb[i] = *(const uint4*)(bptr[i] + k0);
        }
#pragma unroll
        for (int kk = 0; kk < 2; kk++) {
            bf16x8 af[4], bf[2];
#pragma unroll
            for (int s = 0; s < 4; s++)
                af[s] = *(const bf16x8*)(&lA[(wr * 64 + s * 16 + ln) * LDST + kk * 32 + quad * 8]);
#pragma unroll
            for (int j = 0; j < 2; j++)
                bf[j] = *(const bf16x8*)(&lB[(wc * 32 + j * 16 + ln) * LDST + kk * 32 + quad * 8]);
#pragma unroll
            for (int i = 0; i < 4; i++)
#pragma unroll
                for (int j = 0; j < 2; j++)
                    acc[i][j] = __builtin_amdgcn_mfma_f32_16x16x32_bf16(af[i], bf[j], acc[i][j], 0, 0, 0);
        }
    }

#pragma unroll
    for (int j = 0; j < 2; j++) {
        int col = n0 + wc * 32 + j * 16 + ln;
        float bias = b2[e * DIM + col];
#pragma unroll
        for (int i = 0; i < 4; i++) {
#pragma unroll
            for (int r = 0; r < 4; r++) {
                int m = wr * 64 + i * 16 + quad * 4 + r;
                if (m < nvalid) {
                    float vv = (acc[i][j][r] + bias) * lgate[m];
                    atomicAdd(&out[(size_t)ltok2[m] * DIM + col], vv);
                }
            }
        }
    }
}

// ================= r9 fallback GEMMs (known-good at 64.1 MB ws) =================
__global__ __launch_bounds__(256) void ffn1_fast(
    const float* __restrict__ x,
    const unsigned short* __restrict__ w1t,
    const float* __restrict__ b1,
    const int* __restrict__ counts,
    const int* __restrict__ row_tok,
    unsigned short* __restrict__ h)
{
    int id = blockIdx.x;
    int nb = id % (HID / 128);
    int rest = id / (HID / 128);
    int e  = rest % NE;
    int mb = rest / NE;

    int off = 0;
#pragma unroll
    for (int i = 0; i < NE; i++) { int c = clampi(counts[i], 0, NROWS); if (i < e) off += c; }
    int cnt  = clampi(counts[e], 0, NROWS);
    int row0 = mb * 128;
    if (row0 >= cnt) return;
    int nvalid = clampi(cnt - row0, 1, 128);

    __shared__ __align__(16) unsigned short lA[128 * LDST];
    __shared__ __align__(16) unsigned short lB[128 * LDST];
    __shared__ int ltok[128];

    int t = threadIdx.x;
    if (t < 128) {
        int rl = clampi(t, 0, nvalid - 1);
        int idx = clampi(off + row0 + rl, 0, NROWS - 1);
        ltok[t] = clampi(row_tok[idx], 0, N_TOK - 1);
    }
    __syncthreads();

    const int n0 = nb * 128;
    const float* aptr[4];
    const unsigned short* bptr[4];
    int lofs[4];
#pragma unroll
    for (int i = 0; i < 4; i++) {
        int id2 = i * 256 + t;
        int row = id2 >> 3, kc = id2 & 7;
        aptr[i] = x + (size_t)ltok[row] * DIM + kc * 8;
        bptr[i] = w1t + ((size_t)e * HID + n0 + row) * DIM + kc * 8;
        lofs[i] = row * LDST + kc * 8;
    }

    int wv = t >> 6, lane = t & 63, quad = lane >> 4, ln = lane & 15;
    int wr = wv >> 1, wc = wv & 1;
    f32x4 acc[4][4];
#pragma unroll
    for (int i = 0; i < 4; i++)
#pragma unroll
        for (int j = 0; j < 4; j++) acc[i][j] = (f32x4){0.f, 0.f, 0.f, 0.f};

    for (int kt = 0; kt < DIM / 64; kt++) {
        int k0 = kt * 64;
#pragma unroll
        for (int i = 0; i < 4; i++) {
            unsigned short a8[8];
            cvt8(aptr[i] + k0, a8);
            *(uint4*)(&lA[lofs[i]]) = *(uint4*)a8;
            *(uint4*)(&lB[lofs[i]]) = *(const uint4*)(bptr[i] + k0);
        }
        __syncthreads();
#pragma unroll
        for (int kk = 0; kk < 2; kk++) {
            bf16x8 af[4], bf[4];
#pragma unroll
            for (int s = 0; s < 4; s++)
                af[s] = *(const bf16x8*)(&lA[(wr * 64 + s * 16 + ln) * LDST + kk * 32 + quad * 8]);
#pragma unroll
            for (int s = 0; s < 4; s++)
                bf[s] = *(const bf16x8*)(&lB[(wc * 64 + s * 16 + ln) * LDST + kk * 32 + quad * 8]);
#pragma unroll
            for (int i = 0; i < 4; i++)
#pragma unroll
                for (int j = 0; j < 4; j++)
                    acc[i][j] = __builtin_amdgcn_mfma_f32_16x16x32_bf16(af[i], bf[j], acc[i][j], 0, 0, 0);
        }
        __syncthreads();
    }

    int gr0 = off + row0;
#pragma unroll
    for (int j = 0; j < 4; j++) {
        int col = n0 + wc * 64 + j * 16 + ln;
        float bias = b1[e * HID + col];
#pragma unroll
        for (int i = 0; i < 4; i++) {
#pragma unroll
            for (int r = 0; r < 4; r++) {
                int m = wr * 64 + i * 16 + quad * 4 + r;
                if (m < nvalid)
                    h[(size_t)(gr0 + m) * HID + col] = f2bf(fast_gelu(acc[i][j][r] + bias));
            }
        }
    }
}

__global__ __launch_bounds__(256) void ffn2_fast(
    const unsigned short* __restrict__ h,
    const unsigned short* __restrict__ w2t,
    const float* __restrict__ b2,
    const int* __restrict__ counts,
    const int* __restrict__ row_tok,
    const float* __restrict__ row_gate,
    float* __restrict__ out)
{
    int id = blockIdx.x;
    int nb = id % (DIM / 128);
    int rest = id / (DIM / 128);
    int e  = rest % NE;
    int mb = rest / NE;

    int off = 0;
#pragma unroll
    for (int i = 0; i < NE; i++) { int c = clampi(counts[i], 0, NROWS); if (i < e) off += c; }
    int cnt  = clampi(counts[e], 0, NROWS);
    int row0 = mb * 128;
    if (row0 >= cnt) return;
    int nvalid = clampi(cnt - row0, 1, 128);

    __shared__ __align__(16) unsigned short lA[128 * LDST];
    __shared__ __align__(16) unsigned short lB[128 * LDST];
    __shared__ int   ltok2[128];
    __shared__ float lgate[128];

    int t = threadIdx.x;
    if (t < 128) {
        int rl = clampi(t, 0, nvalid - 1);
        int idx = clampi(off + row0 + rl, 0, NROWS - 1);
        ltok2[t] = clampi(row_tok[idx], 0, N_TOK - 1);
        lgate[t] = row_gate[idx];
    }
    __syncthreads();

    const int n0 = nb * 128;
    const unsigned short* aptr[4];
    const unsigned short* bptr[4];
    int lofs[4];
#pragma unroll
    for (int i = 0; i < 4; i++) {
        int id2 = i * 256 + t;
        int row = id2 >> 3, kc = id2 & 7;
        int arow = clampi(off + row0 + clampi(row, 0, nvalid - 1), 0, NROWS - 1);
        aptr[i] = h + (size_t)arow * HID + kc * 8;
        bptr[i] = w2t + ((size_t)e * DIM + n0 + row) * HID + kc * 8;
        lofs[i] = row * LDST + kc * 8;
    }

    int wv = t >> 6, lane = t & 63, quad = lane >> 4, ln = lane & 15;
    int wr = wv >> 1, wc = wv & 1;
    f32x4 acc[4][4];
#pragma unroll
    for (int i = 0; i < 4; i++)
#pragma unroll
        for (int j = 0; j < 4; j++) acc[i][j] = (f32x4){0.f, 0.f, 0.f, 0.f};

    for (int kt = 0; kt < HID / 64; kt++) {
        int k0 = kt * 64;
#pragma unroll
        for (int i = 0; i < 4; i++) {
            *(uint4*)(&lA[lofs[i]]) = *(const uint4*)(aptr[i] + k0);
            *(uint4*)(&lB[lofs[i]]) = *(const uint4*)(bptr[i] + k0);
        }
        __syncthreads();
#pragma unroll
        for (int kk = 0; kk < 2; kk++) {
            bf16x8 af[4], bf[4];
#pragma unroll
            for (int s = 0; s < 4; s++)
                af[s] = *(const bf16x8*)(&lA[(wr * 64 + s * 16 + ln) * LDST + kk * 32 + quad * 8]);
#pragma unroll
            for (int s = 0; s < 4; s++)
                bf[s] = *(const bf16x8*)(&lB[(wc * 64 + s * 16 + ln) * LDST + kk * 32 + quad * 8]);
#pragma unroll
            for (int i = 0; i < 4; i++)
#pragma unroll
                for (int j = 0; j < 4; j++)
                    acc[i][j] = __builtin_amdgcn_mfma_f32_16x16x32_bf16(af[i], bf[j], acc[i][j], 0, 0, 0);
        }
        __syncthreads();
    }

#pragma unroll
    for (int j = 0; j < 4; j++) {
        int col = n0 + wc * 64 + j * 16 + ln;
        float bias = b2[e * DIM + col];
#pragma unroll
        for (int i = 0; i < 4; i++) {
#pragma unroll
            for (int r = 0; r < 4; r++) {
                int m = wr * 64 + i * 16 + quad * 4 + r;
                if (m < nvalid) {
                    float vv = (acc[i][j][r] + bias) * lgate[m];
                    atomicAdd(&out[(size_t)ltok2[m] * DIM + col], vv);
                }
            }
        }
    }
}

__global__ __launch_bounds__(256) void zero_out_kernel(float* __restrict__ out) {
    int i = blockIdx.x * 256 + threadIdx.x;
    out[i] = 0.f;
}

// ================= host =================
extern "C" void kernel_launch(void* const* d_in, const int* in_sizes, int n_in,
                              void* d_out, int out_size, void* d_ws, size_t ws_size,
                              hipStream_t stream) {
    const float* x  = (const float*)d_in[0];
    const float* wg = (const float*)d_in[1];
    const float* w1 = (const float*)d_in[2];
    const float* b1 = (const float*)d_in[3];
    const float* w2 = (const float*)d_in[4];
    const float* b2 = (const float*)d_in[5];
    float* out = (float*)d_out;

    char* ws = (char*)d_ws;
    int*   counts   = (int*)(ws + 0);
    int*   cursors  = (int*)(ws + 64);
    int*   top_e    = (int*)(ws + 256);
    float* top_g    = (float*)(ws + 16640);
    int*   row_tok  = (int*)(ws + 49408);
    float* row_gate = (float*)(ws + 82176);

    // fast2: header 128K | xg 16M | wt 32M | hbuf 32M  = ~80.1 MB
    const size_t XG_OFF       = (size_t)1 << 17;
    const size_t WT2_OFF      = XG_OFF + (size_t)NROWS * DIM * 2;
    const size_t HBUF2_OFF    = WT2_OFF + (size_t)NE * DIM * HID * 2;
    const size_t NEEDED_FAST2 = HBUF2_OFF + (size_t)NROWS * HID * 2;

    // fast (r9): header 128K | wt 32M | hbuf 32M = ~64.1 MB
    const size_t WT_OFF      = (size_t)1 << 17;
    const size_t HBUF_OFF    = WT_OFF + (size_t)NE * DIM * HID * 2;
    const size_t NEEDED_FAST = HBUF_OFF + (size_t)NROWS * HID * 2;

    if (ws_size >= NEEDED_FAST2) {
        unsigned short* xg   = (unsigned short*)(ws + XG_OFF);
        unsigned short* wt   = (unsigned short*)(ws + WT2_OFF);
        unsigned short* hbuf = (unsigned short*)(ws + HBUF2_OFF);

        init_out_kernel<<<dim3(N_TOK * DIM / 1024), dim3(256), 0, stream>>>((int*)ws, (float4*)out);
        gate_kernel<<<dim3(N_TOK / 4), dim3(256), 0, stream>>>(x, wg, counts, top_e, top_g);
        scatter_kernel<<<dim3(N_TOK / 256), dim3(256), 0, stream>>>(counts, cursors, top_e, top_g, row_tok, row_gate);
        xgather_kernel<<<dim3(NROWS * (DIM / 8) / 256), dim3(256), 0, stream>>>(x, row_tok, xg);
        transpose_kernel<<<dim3(DIM / 64, HID / 64, NE), dim3(256), 0, stream>>>(w1, wt, DIM, HID);
        ffn1_fast2<<<dim3(64 * NE * (HID / 128)), dim3(256), 0, stream>>>(xg, wt, b1, counts, hbuf);
        transpose_kernel<<<dim3(HID / 64, DIM / 64, NE), dim3(256), 0, stream>>>(w2, wt, HID, DIM);
        ffn2_fast2<<<dim3(64 * NE * (DIM / 64)), dim3(256), 0, stream>>>(hbuf, wt, b2, counts, row_tok, row_gate, out);
    } else if (ws_size >= NEEDED_FAST) {
        unsigned short* wt   = (unsigned short*)(ws + WT_OFF);
        unsigned short* hbuf = (unsigned short*)(ws + HBUF_OFF);

        init_out_kernel<<<dim3(N_TOK * DIM / 1024), dim3(256), 0, stream>>>((int*)ws, (float4*)out);
        gate_kernel<<<dim3(N_TOK / 4), dim3(256), 0, stream>>>(x, wg, counts, top_e, top_g);
        scatter_kernel<<<dim3(N_TOK / 256), dim3(256), 0, stream>>>(counts, cursors, top_e, top_g, row_tok, row_gate);
        transpose_kernel<<<dim3(DIM / 64, HID / 64, NE), dim3(256), 0, stream>>>(w1, wt, DIM, HID);
        ffn1_fast<<<dim3(64 * NE * (HID / 128)), dim3(256), 0, stream>>>(x, wt, b1, counts, row_tok, hbuf);
        transpose_kernel<<<dim3(HID / 64, DIM / 64, NE), dim3(256), 0, stream>>>(w2, wt, HID, DIM);
        ffn2_fast<<<dim3(64 * NE * (DIM / 128)), dim3(256), 0, stream>>>(hbuf, wt, b2, counts, row_tok, row_gate, out);
    } else {
        zero_out_kernel<<<dim3(N_TOK * DIM / 256), dim3(256), 0, stream>>>(out);
    }
}

// Round 11
// 533.087 us; speedup vs baseline: 1.6827x; 1.6827x over previous
//
#include <hip/hip_runtime.h>
#include <math.h>
#include <stdint.h>

#define N_TOK 4096
#define DIM   1024
#define HID   2048
#define NE    8
#define NROWS (N_TOK * 2)   // 8192 (token, k) assignments
#define LDST  72            // LDS tile stride in shorts (36 dwords; balanced banks, 16B-aligned)

typedef __attribute__((ext_vector_type(8))) short bf16x8;
typedef __attribute__((ext_vector_type(4))) float f32x4;

__device__ __forceinline__ unsigned short f2bf(float f) {
    union { unsigned int i; float f; } v; v.f = f;
    unsigned int u = v.i;
    return (unsigned short)((u + 0x7FFFu + ((u >> 16) & 1u)) >> 16);
}
__device__ __forceinline__ int clampi(int v, int lo, int hi) {
    return v < lo ? lo : (v > hi ? hi : v);
}
__device__ __forceinline__ void cvt8(const float* p, unsigned short* o) {
    float4 a = *(const float4*)p;
    float4 b = *(const float4*)(p + 4);
    o[0] = f2bf(a.x); o[1] = f2bf(a.y); o[2] = f2bf(a.z); o[3] = f2bf(a.w);
    o[4] = f2bf(b.x); o[5] = f2bf(b.y); o[6] = f2bf(b.z); o[7] = f2bf(b.w);
}
__device__ __forceinline__ float fast_gelu(float v) {
    float c = 0.7978845608028654f * (v + 0.044715f * v * v * v);
    float t = 1.f - 2.f / (1.f + __expf(2.f * c));   // tanh(c)
    return 0.5f * v * (1.f + t);
}

// ---------------- init: zero counts + cursors ----------------
__global__ void init_hdr_kernel(int* __restrict__ hdr) {
    if (threadIdx.x < 32) hdr[threadIdx.x] = 0;
}

// ---------------- gating: one wave per token, pure fp32 ----------------
__global__ __launch_bounds__(256) void gate_kernel(
    const float* __restrict__ x, const float* __restrict__ wg,
    int* __restrict__ counts, unsigned short* __restrict__ top_e, float* __restrict__ top_g)
{
    int wave = threadIdx.x >> 6;
    int lane = threadIdx.x & 63;
    int n = blockIdx.x * 4 + wave;
    if (n >= N_TOK) return;
    float acc[NE];
#pragma unroll
    for (int e = 0; e < NE; e++) acc[e] = 0.f;
    const float* xrow = x + (size_t)n * DIM;
    for (int d = lane; d < DIM; d += 64) {
        float xv = xrow[d];
        float4 wa = *(const float4*)(wg + (size_t)d * NE);
        float4 wb = *(const float4*)(wg + (size_t)d * NE + 4);
        acc[0] += xv * wa.x; acc[1] += xv * wa.y;
        acc[2] += xv * wa.z; acc[3] += xv * wa.w;
        acc[4] += xv * wb.x; acc[5] += xv * wb.y;
        acc[6] += xv * wb.z; acc[7] += xv * wb.w;
    }
#pragma unroll
    for (int e = 0; e < NE; e++) {
        float v = acc[e];
#pragma unroll
        for (int off = 32; off > 0; off >>= 1) v += __shfl_xor(v, off, 64);
        acc[e] = v;
    }
    if (lane == 0) {
        int e0 = 0; float v0 = acc[0];
#pragma unroll
        for (int e = 1; e < NE; e++) if (acc[e] > v0) { v0 = acc[e]; e0 = e; }
        int e1 = (e0 == 0) ? 1 : 0; float v1 = acc[e1];
#pragma unroll
        for (int e = 0; e < NE; e++) if (e != e0 && acc[e] > v1) { v1 = acc[e]; e1 = e; }
        float s = expf(v1 - v0);
        float g0 = 1.f / (1.f + s);
        float g1 = s / (1.f + s);
        atomicAdd(&counts[e0], 1);
        atomicAdd(&counts[e1], 1);
        top_e[n] = (unsigned short)(e0 | (e1 << 8));
        top_g[2 * n + 0] = g0;
        top_g[2 * n + 1] = g1;
    }
}

// ---------------- scatter: per-expert row lists; row_tok = (n<<1)|k ----------------
__global__ __launch_bounds__(256) void scatter_kernel(
    const int* __restrict__ counts, int* __restrict__ cursors,
    const unsigned short* __restrict__ top_e, const float* __restrict__ top_g,
    int* __restrict__ row_tok, float* __restrict__ row_gate)
{
    int n = blockIdx.x * 256 + threadIdx.x;
    if (n >= N_TOK) return;
    int off[NE]; int a = 0;
#pragma unroll
    for (int e = 0; e < NE; e++) { off[e] = a; a += clampi(counts[e], 0, NROWS); }
    int te = top_e[n];
#pragma unroll
    for (int k = 0; k < 2; k++) {
        int e = clampi((k == 0) ? (te & 0xFF) : ((te >> 8) & 0xFF), 0, NE - 1);
        int pos = atomicAdd(&cursors[e], 1);
        int r = clampi(off[e] + pos, 0, NROWS - 1);
        row_tok[r]  = (n << 1) | k;
        row_gate[r] = top_g[2 * n + k];
    }
}

// ---------------- transpose+cast: in[e][K][N] fp32 -> out[e][N][K] bf16 ----------------
__global__ __launch_bounds__(256) void transpose_kernel(
    const float* __restrict__ in, unsigned short* __restrict__ outp, int K, int N)
{
    int e  = blockIdx.z;
    int kb = blockIdx.x;
    int nb = blockIdx.y;
    __shared__ __align__(16) unsigned short tile[64 * LDST];
    int t = threadIdx.x;

    int r = t >> 2, cq = t & 3;
    const float* sp = in + ((size_t)e * K + kb * 64 + r) * N + nb * 64 + cq * 16;
    unsigned short v[16];
    cvt8(sp, v);
    cvt8(sp + 8, v + 8);
    *(uint4*)(&tile[r * LDST + cq * 16 + 0]) = *(uint4*)(v + 0);
    *(uint4*)(&tile[r * LDST + cq * 16 + 8]) = *(uint4*)(v + 8);
    __syncthreads();

    int c = t >> 2, kq = t & 3;
    unsigned short o[16];
#pragma unroll
    for (int i = 0; i < 16; i++) o[i] = tile[(kq * 16 + i) * LDST + c];
    unsigned short* dp = outp + ((size_t)e * N + nb * 64 + c) * K + kb * 64 + kq * 16;
    *(uint4*)(dp + 0) = *(uint4*)(o + 0);
    *(uint4*)(dp + 8) = *(uint4*)(o + 8);
}

// ---------------- FFN1: 128x128 tile, BK=64, w1t bf16 (r9-proven body) ----------------
__global__ __launch_bounds__(256) void ffn1_fast(
    const float* __restrict__ x,
    const unsigned short* __restrict__ w1t,   // [e][H][D] bf16
    const float* __restrict__ b1,
    const int* __restrict__ counts,
    const int* __restrict__ row_tok,
    unsigned short* __restrict__ h)
{
    int id = blockIdx.x;
    int nb = id % (HID / 128);
    int rest = id / (HID / 128);
    int e  = rest % NE;
    int mb = rest / NE;

    int off = 0;
#pragma unroll
    for (int i = 0; i < NE; i++) { int c = clampi(counts[i], 0, NROWS); if (i < e) off += c; }
    int cnt  = clampi(counts[e], 0, NROWS);
    int row0 = mb * 128;
    if (row0 >= cnt) return;
    int nvalid = clampi(cnt - row0, 1, 128);

    __shared__ __align__(16) unsigned short lA[128 * LDST];
    __shared__ __align__(16) unsigned short lB[128 * LDST];
    __shared__ int ltok[128];

    int t = threadIdx.x;
    if (t < 128) {
        int rl = clampi(t, 0, nvalid - 1);
        int idx = clampi(off + row0 + rl, 0, NROWS - 1);
        ltok[t] = clampi(row_tok[idx] >> 1, 0, N_TOK - 1);   // decode token
    }
    __syncthreads();

    const int n0 = nb * 128;
    const float* aptr[4];
    const unsigned short* bptr[4];
    int lofs[4];
#pragma unroll
    for (int i = 0; i < 4; i++) {
        int id2 = i * 256 + t;
        int row = id2 >> 3, kc = id2 & 7;
        aptr[i] = x + (size_t)ltok[row] * DIM + kc * 8;
        bptr[i] = w1t + ((size_t)e * HID + n0 + row) * DIM + kc * 8;
        lofs[i] = row * LDST + kc * 8;
    }

    int wv = t >> 6, lane = t & 63, quad = lane >> 4, ln = lane & 15;
    int wr = wv >> 1, wc = wv & 1;
    f32x4 acc[4][4];
#pragma unroll
    for (int i = 0; i < 4; i++)
#pragma unroll
        for (int j = 0; j < 4; j++) acc[i][j] = (f32x4){0.f, 0.f, 0.f, 0.f};

    for (int kt = 0; kt < DIM / 64; kt++) {
        int k0 = kt * 64;
#pragma unroll
        for (int i = 0; i < 4; i++) {
            unsigned short a8[8];
            cvt8(aptr[i] + k0, a8);
            *(uint4*)(&lA[lofs[i]]) = *(uint4*)a8;
            *(uint4*)(&lB[lofs[i]]) = *(const uint4*)(bptr[i] + k0);
        }
        __syncthreads();
#pragma unroll
        for (int kk = 0; kk < 2; kk++) {
            bf16x8 af[4], bf[4];
#pragma unroll
            for (int s = 0; s < 4; s++)
                af[s] = *(const bf16x8*)(&lA[(wr * 64 + s * 16 + ln) * LDST + kk * 32 + quad * 8]);
#pragma unroll
            for (int s = 0; s < 4; s++)
                bf[s] = *(const bf16x8*)(&lB[(wc * 64 + s * 16 + ln) * LDST + kk * 32 + quad * 8]);
#pragma unroll
            for (int i = 0; i < 4; i++)
#pragma unroll
                for (int j = 0; j < 4; j++)
                    acc[i][j] = __builtin_amdgcn_mfma_f32_16x16x32_bf16(af[i], bf[j], acc[i][j], 0, 0, 0);
        }
        __syncthreads();
    }

    int gr0 = off + row0;
#pragma unroll
    for (int j = 0; j < 4; j++) {
        int col = n0 + wc * 64 + j * 16 + ln;
        float bias = b1[e * HID + col];
#pragma unroll
        for (int i = 0; i < 4; i++) {
#pragma unroll
            for (int r = 0; r < 4; r++) {
                int m = wr * 64 + i * 16 + quad * 4 + r;
                if (m < nvalid)
                    h[(size_t)(gr0 + m) * HID + col] = f2bf(fast_gelu(acc[i][j][r] + bias));
            }
        }
    }
}

// ---------------- FFN2: 128x128 tile, plain-store slot-split epilogue (NO atomics) ----------------
__global__ __launch_bounds__(256) void ffn2_fast3(
    const unsigned short* __restrict__ h,
    const unsigned short* __restrict__ w2t,   // [e][D][H] bf16
    const float* __restrict__ b2,
    const int* __restrict__ counts,
    const int* __restrict__ row_tok,
    const float* __restrict__ row_gate,
    float* __restrict__ out,                  // k=0 slot
    float* __restrict__ ybuf1)                // k=1 slot
{
    int id = blockIdx.x;
    int nb = id % (DIM / 128);
    int rest = id / (DIM / 128);
    int e  = rest % NE;
    int mb = rest / NE;

    int off = 0;
#pragma unroll
    for (int i = 0; i < NE; i++) { int c = clampi(counts[i], 0, NROWS); if (i < e) off += c; }
    int cnt  = clampi(counts[e], 0, NROWS);
    int row0 = mb * 128;
    if (row0 >= cnt) return;
    int nvalid = clampi(cnt - row0, 1, 128);

    __shared__ __align__(16) unsigned short lA[128 * LDST];
    __shared__ __align__(16) unsigned short lB[128 * LDST];
    __shared__ int   ltok2[128];              // (n<<1)|k
    __shared__ float lgate[128];

    int t = threadIdx.x;
    if (t < 128) {
        int rl = clampi(t, 0, nvalid - 1);
        int idx = clampi(off + row0 + rl, 0, NROWS - 1);
        ltok2[t] = clampi(row_tok[idx], 0, 2 * N_TOK - 1);
        lgate[t] = row_gate[idx];
    }
    __syncthreads();

    const int n0 = nb * 128;
    const unsigned short* aptr[4];
    const unsigned short* bptr[4];
    int lofs[4];
#pragma unroll
    for (int i = 0; i < 4; i++) {
        int id2 = i * 256 + t;
        int row = id2 >> 3, kc = id2 & 7;
        int arow = clampi(off + row0 + row, 0, NROWS - 1);
        aptr[i] = h + (size_t)arow * HID + kc * 8;
        bptr[i] = w2t + ((size_t)e * DIM + n0 + row) * HID + kc * 8;
        lofs[i] = row * LDST + kc * 8;
    }

    int wv = t >> 6, lane = t & 63, quad = lane >> 4, ln = lane & 15;
    int wr = wv >> 1, wc = wv & 1;
    f32x4 acc[4][4];
#pragma unroll
    for (int i = 0; i < 4; i++)
#pragma unroll
        for (int j = 0; j < 4; j++) acc[i][j] = (f32x4){0.f, 0.f, 0.f, 0.f};

    for (int kt = 0; kt < HID / 64; kt++) {
        int k0 = kt * 64;
#pragma unroll
        for (int i = 0; i < 4; i++) {
            *(uint4*)(&lA[lofs[i]]) = *(const uint4*)(aptr[i] + k0);
            *(uint4*)(&lB[lofs[i]]) = *(const uint4*)(bptr[i] + k0);
        }
        __syncthreads();
#pragma unroll
        for (int kk = 0; kk < 2; kk++) {
            bf16x8 af[4], bf[4];
#pragma unroll
            for (int s = 0; s < 4; s++)
                af[s] = *(const bf16x8*)(&lA[(wr * 64 + s * 16 + ln) * LDST + kk * 32 + quad * 8]);
#pragma unroll
            for (int s = 0; s < 4; s++)
                bf[s] = *(const bf16x8*)(&lB[(wc * 64 + s * 16 + ln) * LDST + kk * 32 + quad * 8]);
#pragma unroll
            for (int i = 0; i < 4; i++)
#pragma unroll
                for (int j = 0; j < 4; j++)
                    acc[i][j] = __builtin_amdgcn_mfma_f32_16x16x32_bf16(af[i], bf[j], acc[i][j], 0, 0, 0);
        }
        __syncthreads();
    }

#pragma unroll
    for (int j = 0; j < 4; j++) {
        int col = n0 + wc * 64 + j * 16 + ln;
        float bias = b2[e * DIM + col];
#pragma unroll
        for (int i = 0; i < 4; i++) {
#pragma unroll
            for (int r = 0; r < 4; r++) {
                int m = wr * 64 + i * 16 + quad * 4 + r;
                if (m < nvalid) {
                    int rt  = ltok2[m];
                    int tok = rt >> 1;
                    float vv = (acc[i][j][r] + bias) * lgate[m];
                    float* dst = (rt & 1) ? ybuf1 : out;    // exactly one writer per (tok,col,k)
                    dst[(size_t)tok * DIM + col] = vv;
                }
            }
        }
    }
}

// ---------------- combine: out += ybuf1 ----------------
__global__ __launch_bounds__(256) void combine_kernel(
    float4* __restrict__ out4, const float4* __restrict__ y4)
{
    int i = blockIdx.x * 256 + threadIdx.x;   // 1M float4
    float4 a = out4[i];
    float4 b = y4[i];
    out4[i] = make_float4(a.x + b.x, a.y + b.y, a.z + b.z, a.w + b.w);
}

__global__ __launch_bounds__(256) void zero_out_kernel(float* __restrict__ out) {
    int i = blockIdx.x * 256 + threadIdx.x;
    out[i] = 0.f;
}

// ================= host =================
extern "C" void kernel_launch(void* const* d_in, const int* in_sizes, int n_in,
                              void* d_out, int out_size, void* d_ws, size_t ws_size,
                              hipStream_t stream) {
    const float* x  = (const float*)d_in[0];
    const float* wg = (const float*)d_in[1];
    const float* w1 = (const float*)d_in[2];
    const float* b1 = (const float*)d_in[3];
    const float* w2 = (const float*)d_in[4];
    const float* b2 = (const float*)d_in[5];
    float* out = (float*)d_out;

    // Header (first 128 KB):
    //   [0,64)        counts (8 int)
    //   [64,128)      cursors (8 int)
    //   [256,8448)    top_e  ushort[4096]
    //   [8448,41216)  top_g  f32[8192]
    //   [41216,73984) row_tok int[8192]   ((n<<1)|k)
    //   [73984,106752) row_gate f32[8192]
    // Data: wt 32M | hbuf 32M | ybuf1 16M  => total 84,017,152 B (== r10's proven size)
    char* ws = (char*)d_ws;
    int*            counts   = (int*)(ws + 0);
    int*            cursors  = (int*)(ws + 64);
    unsigned short* top_e    = (unsigned short*)(ws + 256);
    float*          top_g    = (float*)(ws + 8448);
    int*            row_tok  = (int*)(ws + 41216);
    float*          row_gate = (float*)(ws + 73984);

    const size_t WT_OFF    = (size_t)1 << 17;
    const size_t HBUF_OFF  = WT_OFF + (size_t)NE * DIM * HID * 2;      // +32M
    const size_t YBUF_OFF  = HBUF_OFF + (size_t)NROWS * HID * 2;       // +32M
    const size_t NEEDED    = YBUF_OFF + (size_t)N_TOK * DIM * 4;       // +16M = 84,017,152

    if (ws_size < NEEDED) {
        zero_out_kernel<<<dim3(N_TOK * DIM / 256), dim3(256), 0, stream>>>(out);
        return;
    }

    unsigned short* wt    = (unsigned short*)(ws + WT_OFF);
    unsigned short* hbuf  = (unsigned short*)(ws + HBUF_OFF);
    float*          ybuf1 = (float*)(ws + YBUF_OFF);

    init_hdr_kernel<<<dim3(1), dim3(64), 0, stream>>>((int*)ws);
    gate_kernel<<<dim3(N_TOK / 4), dim3(256), 0, stream>>>(x, wg, counts, top_e, top_g);
    scatter_kernel<<<dim3(N_TOK / 256), dim3(256), 0, stream>>>(counts, cursors, top_e, top_g, row_tok, row_gate);
    // w1 [e][D][H] -> w1T [e][H][D]
    transpose_kernel<<<dim3(DIM / 64, HID / 64, NE), dim3(256), 0, stream>>>(w1, wt, DIM, HID);
    ffn1_fast<<<dim3(64 * NE * (HID / 128)), dim3(256), 0, stream>>>(x, wt, b1, counts, row_tok, hbuf);
    // w2 [e][H][D] -> w2T [e][D][H]
    transpose_kernel<<<dim3(HID / 64, DIM / 64, NE), dim3(256), 0, stream>>>(w2, wt, HID, DIM);
    ffn2_fast3<<<dim3(64 * NE * (DIM / 128)), dim3(256), 0, stream>>>(hbuf, wt, b2, counts, row_tok, row_gate, out, ybuf1);
    combine_kernel<<<dim3(N_TOK * DIM / 1024), dim3(256), 0, stream>>>((float4*)out, (const float4*)ybuf1);
}